// Round 16
// baseline (289.709 us; speedup 1.0000x reference)
//
#include <hip/hip_runtime.h>
#include <hip/hip_bf16.h>
#include <stdint.h>

#define CDIM 768
#define HDIM 48

typedef float  f32x4  __attribute__((ext_vector_type(4)));
typedef short  bf16x8 __attribute__((ext_vector_type(8)));
typedef unsigned short u16x4 __attribute__((ext_vector_type(4)));

__device__ __forceinline__ unsigned short f2bf(float x) {
    __hip_bfloat16 h = __float2bfloat16(x);   // HW RNE convert
    return *reinterpret_cast<unsigned short*>(&h);
}
__device__ __forceinline__ float b2f(short s) {
    union { float f; uint32_t u; } v;
    v.u = ((uint32_t)(unsigned short)s) << 16;
    return v.f;
}
#define SB0() __builtin_amdgcn_sched_barrier(0)

// ---------------- prep: pack weights into MFMA fragment order ----------------
// (unchanged — verified correct since R1)
__global__ __launch_bounds__(256) void prep_kernel(
    const float* __restrict__ W1, const float* __restrict__ b1,
    const float* __restrict__ W2,
    const float* __restrict__ gamma, const float* __restrict__ beta,
    unsigned short* __restrict__ w1p, unsigned short* __restrict__ w2p,
    float* __restrict__ b1p, float* __restrict__ cs1)
{
    const int blk = blockIdx.x, tid = threadIdx.x;
    const int l = tid & 63;
    if (blk < 18) {                       // 72 W1 frags, 4/block
        const int fid = blk * 4 + (tid >> 6);
        const int kt = fid / 3, nt = fid % 3;
        const int k0 = kt * 32 + 8 * (l >> 4);
        const int n  = nt * 16 + (l & 15);
        bf16x8 v;
        #pragma unroll
        for (int b = 0; b < 8; ++b) {
            const int k = k0 + b;
            v[b] = (short)f2bf(gamma[k] * W1[k * HDIM + n]);
        }
        *reinterpret_cast<bf16x8*>(w1p + (size_t)(fid * 64 + l) * 8) = v;
    } else if (blk < 42) {                // 96 W2 frags, 4/block
        const int fid = (blk - 18) * 4 + (tid >> 6);
        const int kt = fid / 48, nt = fid % 48;
        const int k0 = kt * 32 + 8 * (l >> 4);
        const int n  = nt * 16 + (l & 15);
        bf16x8 v;
        #pragma unroll
        for (int b = 0; b < 8; ++b) {
            const int k = k0 + b;
            const float w = (k < HDIM) ? W2[k * CDIM + n] : 0.0f;
            v[b] = (short)f2bf(w);
        }
        *reinterpret_cast<bf16x8*>(w2p + (size_t)(fid * 64 + l) * 8) = v;
    } else {                              // b1p / cs1 reductions
        const int j = tid >> 2, p = tid & 3;
        float sb = 0.f, sg = 0.f;
        if (j < HDIM) {
            for (int c = p * 192; c < (p + 1) * 192; ++c) {
                const float w = W1[c * HDIM + j];
                sb += beta[c]  * w;
                sg += gamma[c] * w;
            }
        }
        sb += __shfl_xor(sb, 1); sb += __shfl_xor(sb, 2);
        sg += __shfl_xor(sg, 1); sg += __shfl_xor(sg, 2);
        if (p == 0 && j < HDIM) { b1p[j] = b1[j] + sb; cs1[j] = sg; }
    }
}

// ---------------- main fused kernel ----------------
// R16 = R13 (wave-contiguous HBM + LDS layout decoupling + clean FIFO) at
// 1.5x the occupancy via an LDS diet: 8448 B/wave instead of 16896.
//  - x-stage: SINGLE buffer [16][264] bf16. Safe without dbuf because the
//    ds_write of third j+1 comes AFTER the ds_reads of third j in program
//    order, and per-wave LDS ops to aliasing addresses execute in order.
//  - out-stage: halves [16][132] f32 = 8448 B (same buffer); stores become
//    512 B-contiguous runs (2 rows per 1 KB instruction).
//  - 37.2 KB/block + __launch_bounds__(256,3) -> 3 blocks/CU = 12 waves/CU
//    (R13: 8). VGPR cap 170 (R13 used 128-176) -> spill-safe.
__global__ __launch_bounds__(256, 3) void mlp_kernel(
    const float* __restrict__ x,
    const float* __restrict__ b2g,
    const unsigned short* __restrict__ w1p,
    const unsigned short* __restrict__ w2p,
    const float* __restrict__ b1p,
    const float* __restrict__ cs1,
    float* __restrict__ out)
{
    __shared__ __align__(16) char  lds_buf[4][8448];   // per-wave: x stage / hid / out half
    __shared__ __align__(16) float lds_b2[CDIM];
    __shared__ __align__(16) float lds_b1[HDIM];
    __shared__ __align__(16) float lds_cs[HDIM];

    const int tid  = threadIdx.x;
    const int w    = tid >> 6;
    const int l    = tid & 63;
    const int lrow = l & 15;
    const int lg   = l >> 4;

    if (tid < 192)       reinterpret_cast<f32x4*>(lds_b2)[tid]       = reinterpret_cast<const f32x4*>(b2g)[tid];
    else if (tid < 204)  reinterpret_cast<f32x4*>(lds_b1)[tid - 192] = reinterpret_cast<const f32x4*>(b1p)[tid - 192];
    else if (tid < 216)  reinterpret_cast<f32x4*>(lds_cs)[tid - 204] = reinterpret_cast<const f32x4*>(cs1)[tid - 204];
    __syncthreads();

    char* const wb = lds_buf[w];
    const size_t m0 = ((size_t)blockIdx.x * 4 + w) * 16;
    const char* const xg = (const char*)x + m0 * 3072;

    const bf16x8* __restrict__ w1f = reinterpret_cast<const bf16x8*>(w1p);
    const bf16x8* __restrict__ w2f = reinterpret_cast<const bf16x8*>(w2p);

    // ================= G1: stage third 0 (1 KB contiguous per instr) ==========
    {
        f32x4 xv[16];
        #pragma unroll
        for (int r = 0; r < 16; ++r)
            xv[r] = *reinterpret_cast<const f32x4*>(xg + r * 3072 + l * 16);
        #pragma unroll
        for (int r = 0; r < 16; ++r) {
            u16x4 pk;
            #pragma unroll
            for (int e = 0; e < 4; ++e) pk[e] = f2bf(xv[r][e]);
            *reinterpret_cast<u16x4*>(wb + r * 528 + l * 8) = pk;   // [16][264] bf16
        }
    }

    f32x4 acc1[3];
    #pragma unroll
    for (int nt = 0; nt < 3; ++nt) { acc1[nt][0]=0.f; acc1[nt][1]=0.f; acc1[nt][2]=0.f; acc1[nt][3]=0.f; }
    float rs = 0.f, rq = 0.f;

    #pragma unroll 1
    for (int j = 0; j < 3; ++j) {
        // (a) w1 fragments for this third — OLDEST in FIFO
        bf16x8 w1v[24];
        #pragma unroll
        for (int q = 0; q < 24; ++q) w1v[q] = w1f[(j * 24 + q) * 64 + l];
        // (b) contiguous stage-loads for third j+1 (HBM stream, youngest)
        f32x4 xn[16];
        if (j < 2) {
            #pragma unroll
            for (int r = 0; r < 16; ++r)
                xn[r] = *reinterpret_cast<const f32x4*>(xg + r * 3072 + (j + 1) * 1024 + l * 16);
        }
        SB0();   // pin loads above compute
        // (c) compute third j from wb: 8 ktiles, frags via ds_read_b128
        #pragma unroll
        for (int ktl = 0; ktl < 8; ++ktl) {
            const bf16x8 xf = *reinterpret_cast<const bf16x8*>(wb + lrow * 528 + ktl * 64 + lg * 16);
            #pragma unroll
            for (int e = 0; e < 8; ++e) { const float xe = b2f(xf[e]); rs += xe; rq += xe * xe; }
            acc1[0] = __builtin_amdgcn_mfma_f32_16x16x32_bf16(w1v[ktl*3+0], xf, acc1[0], 0, 0, 0);
            acc1[1] = __builtin_amdgcn_mfma_f32_16x16x32_bf16(w1v[ktl*3+1], xf, acc1[1], 0, 0, 0);
            acc1[2] = __builtin_amdgcn_mfma_f32_16x16x32_bf16(w1v[ktl*3+2], xf, acc1[2], 0, 0, 0);
        }
        // (d) land third j+1 into the SAME buffer (per-wave LDS program order:
        //     these ds_writes issue after (c)'s ds_reads -> no hazard)
        if (j < 2) {
            #pragma unroll
            for (int r = 0; r < 16; ++r) {
                u16x4 pk;
                #pragma unroll
                for (int e = 0; e < 4; ++e) pk[e] = f2bf(xn[r][e]);
                *reinterpret_cast<u16x4*>(wb + r * 528 + l * 8) = pk;
            }
        }
    }

    // ---- stats reduce + LN fixup + QuickGELU -> hid (aliases wb) ----
    rs += __shfl_xor(rs, 16); rs += __shfl_xor(rs, 32);
    rq += __shfl_xor(rq, 16); rq += __shfl_xor(rq, 32);
    const float mu   = rs * (1.f / 768.f);
    const float var  = rq * (1.f / 768.f) - mu * mu;
    const float rstd = rsqrtf(var + 1e-5f);

    unsigned short* const hid = reinterpret_cast<unsigned short*>(wb);  // [16][72]
    *reinterpret_cast<unsigned long long*>(hid + (l >> 2) * 72 + 48 + (l & 3) * 4) = 0ull;
    #pragma unroll
    for (int nt = 0; nt < 3; ++nt) {
        const int c4 = nt * 16 + 4 * lg;
        const f32x4 bb = *reinterpret_cast<const f32x4*>(&lds_b1[c4]);
        const f32x4 cs = *reinterpret_cast<const f32x4*>(&lds_cs[c4]);
        u16x4 pk;
        #pragma unroll
        for (int r = 0; r < 4; ++r) {
            const float h = rstd * (acc1[nt][r] - mu * cs[r]) + bb[r];
            const float g = h / (1.f + __expf(-1.702f * h));
            pk[r] = f2bf(g);
        }
        *reinterpret_cast<u16x4*>(hid + lrow * 72 + c4) = pk;
    }
    // wave-synchronous handoff into regs (hid area reused right after)
    const bf16x8 a2_0 = *reinterpret_cast<const bf16x8*>(hid + lrow * 72 + 8 * lg);
    const bf16x8 a2_1 = *reinterpret_cast<const bf16x8*>(hid + lrow * 72 + 8 * lg + 32);

    // ================= G2: 6 halves x 8 ctiles; 512 B-contiguous stores =======
    const float* __restrict__ xres = x + (m0 + lrow) * CDIM;
    #pragma unroll 1
    for (int t6 = 0; t6 < 6; ++t6) {
        f32x4 res[8];
        #pragma unroll
        for (int i = 0; i < 8; ++i)
            res[i] = *reinterpret_cast<const f32x4*>(xres + (t6 * 8 + i) * 16 + 4 * lg);
        #pragma unroll
        for (int i = 0; i < 8; ++i) {
            const int ct = t6 * 8 + i;
            f32x4 a = {0.f, 0.f, 0.f, 0.f};
            a = __builtin_amdgcn_mfma_f32_16x16x32_bf16(w2f[ct * 64 + l],        a2_0, a, 0, 0, 0);
            a = __builtin_amdgcn_mfma_f32_16x16x32_bf16(w2f[(48 + ct) * 64 + l], a2_1, a, 0, 0, 0);
            const f32x4 bb = *reinterpret_cast<const f32x4*>(&lds_b2[ct * 16 + 4 * lg]);
            f32x4 o;
            #pragma unroll
            for (int r = 0; r < 4; ++r) o[r] = a[r] + bb[r] + res[i][r];
            // out half stage [16][132] f32 (fragment-order write)
            *reinterpret_cast<f32x4*>(wb + lrow * 528 + (i * 16 + 4 * lg) * 4) = o;
        }
        // contiguous stores: 8 instrs x 1 KB, each covering 2 rows x 512 B
        #pragma unroll
        for (int r = 0; r < 8; ++r) {
            const int rr = 2 * r + (l >> 5);
            const f32x4 v = *reinterpret_cast<const f32x4*>(wb + rr * 528 + (l & 31) * 16);
            *reinterpret_cast<f32x4*>((char*)out + (m0 + rr) * 3072 + t6 * 512 + (l & 31) * 16) = v;
        }
    }
}

extern "C" void kernel_launch(void* const* d_in, const int* in_sizes, int n_in,
                              void* d_out, int out_size, void* d_ws, size_t ws_size,
                              hipStream_t stream)
{
    const float* x     = (const float*)d_in[0];
    const float* W1    = (const float*)d_in[1];
    const float* b1    = (const float*)d_in[2];
    const float* W2    = (const float*)d_in[3];
    const float* b2    = (const float*)d_in[4];
    const float* gamma = (const float*)d_in[5];
    const float* beta  = (const float*)d_in[6];
    float* out = (float*)d_out;

    unsigned short* w1p = (unsigned short*)d_ws;     // 72 frags * 1 KB = 73728 B
    unsigned short* w2p = w1p + 24 * 3 * 64 * 8;     // 96 frags * 1 KB = 98304 B
    float* b1p = (float*)(w2p + 2 * 48 * 64 * 8);    // 48 f32
    float* cs1 = b1p + 64;                           // 48 f32 (16B-aligned gap)

    const int M = in_sizes[0] / CDIM;   // 131072 rows
    const int blocks = M / 64;          // 2048 blocks x 4 waves x 16 rows

    prep_kernel<<<dim3(43), dim3(256), 0, stream>>>(W1, b1, W2, gamma, beta, w1p, w2p, b1p, cs1);
    mlp_kernel<<<dim3(blocks), dim3(256), 0, stream>>>(x, b2, w1p, w2p, b1p, cs1, out);
}

// Round 17
// 228.094 us; speedup vs baseline: 1.2701x; 1.2701x over previous
//
#include <hip/hip_runtime.h>
#include <hip/hip_bf16.h>
#include <stdint.h>

#define CDIM 768
#define HDIM 48

typedef float  f32x4  __attribute__((ext_vector_type(4)));
typedef short  bf16x8 __attribute__((ext_vector_type(8)));
typedef unsigned short u16x4 __attribute__((ext_vector_type(4)));

__device__ __forceinline__ unsigned short f2bf(float x) {
    __hip_bfloat16 h = __float2bfloat16(x);   // HW RNE convert
    return *reinterpret_cast<unsigned short*>(&h);
}
__device__ __forceinline__ float b2f(short s) {
    union { float f; uint32_t u; } v;
    v.u = ((uint32_t)(unsigned short)s) << 16;
    return v.f;
}
#define SB0() __builtin_amdgcn_sched_barrier(0)

// ---------------- prep: pack weights into MFMA fragment order ----------------
// (unchanged — verified correct since R1)
__global__ __launch_bounds__(256) void prep_kernel(
    const float* __restrict__ W1, const float* __restrict__ b1,
    const float* __restrict__ W2,
    const float* __restrict__ gamma, const float* __restrict__ beta,
    unsigned short* __restrict__ w1p, unsigned short* __restrict__ w2p,
    float* __restrict__ b1p, float* __restrict__ cs1)
{
    const int blk = blockIdx.x, tid = threadIdx.x;
    const int l = tid & 63;
    if (blk < 18) {                       // 72 W1 frags, 4/block
        const int fid = blk * 4 + (tid >> 6);
        const int kt = fid / 3, nt = fid % 3;
        const int k0 = kt * 32 + 8 * (l >> 4);
        const int n  = nt * 16 + (l & 15);
        bf16x8 v;
        #pragma unroll
        for (int b = 0; b < 8; ++b) {
            const int k = k0 + b;
            v[b] = (short)f2bf(gamma[k] * W1[k * HDIM + n]);
        }
        *reinterpret_cast<bf16x8*>(w1p + (size_t)(fid * 64 + l) * 8) = v;
    } else if (blk < 42) {                // 96 W2 frags, 4/block
        const int fid = (blk - 18) * 4 + (tid >> 6);
        const int kt = fid / 48, nt = fid % 48;
        const int k0 = kt * 32 + 8 * (l >> 4);
        const int n  = nt * 16 + (l & 15);
        bf16x8 v;
        #pragma unroll
        for (int b = 0; b < 8; ++b) {
            const int k = k0 + b;
            const float w = (k < HDIM) ? W2[k * CDIM + n] : 0.0f;
            v[b] = (short)f2bf(w);
        }
        *reinterpret_cast<bf16x8*>(w2p + (size_t)(fid * 64 + l) * 8) = v;
    } else {                              // b1p / cs1 reductions
        const int j = tid >> 2, p = tid & 3;
        float sb = 0.f, sg = 0.f;
        if (j < HDIM) {
            for (int c = p * 192; c < (p + 1) * 192; ++c) {
                const float w = W1[c * HDIM + j];
                sb += beta[c]  * w;
                sg += gamma[c] * w;
            }
        }
        sb += __shfl_xor(sb, 1); sb += __shfl_xor(sb, 2);
        sg += __shfl_xor(sg, 1); sg += __shfl_xor(sg, 2);
        if (p == 0 && j < HDIM) { b1p[j] = b1[j] + sb; cs1[j] = sg; }
    }
}

// ---------------- main fused kernel ----------------
// R17 = R13 verbatim (measured optimum, 228.5 µs). Wave-contiguous HBM access
// (every read/write instruction covers 1 KB contiguous) with MFMA fragment
// layout decoupled via per-wave LDS tile buffers:
//   G1: rows -> LDS bf16 [16][264] (thirds, double-buffered) -> ds_read frags
//   G2: epilogue -> LDS f32 [16][260] -> contiguous 1 KB row stores
// Per-third FIFO monotone: [w1 frags (L2)] then [x stage loads (HBM)], consumed
// in that order. 8 waves/CU (2 blocks) = the L2-residency sweet spot: the G2
// residual re-read stays cache-absorbed (FETCH = one x pass exactly); 12
// waves/CU (R16) thrashes L2 (+90 MB HBM), 4 waves/CU (R14) starves TLP.
__global__ __launch_bounds__(256, 2) void mlp_kernel(
    const float* __restrict__ x,
    const float* __restrict__ b2g,
    const unsigned short* __restrict__ w1p,
    const unsigned short* __restrict__ w2p,
    const float* __restrict__ b1p,
    const float* __restrict__ cs1,
    float* __restrict__ out)
{
    __shared__ __align__(16) char  lds_buf[4][16896];  // per-wave: x dbuf / hid / out-third
    __shared__ __align__(16) float lds_b2[CDIM];
    __shared__ __align__(16) float lds_b1[HDIM];
    __shared__ __align__(16) float lds_cs[HDIM];

    const int tid  = threadIdx.x;
    const int w    = tid >> 6;
    const int l    = tid & 63;
    const int lrow = l & 15;
    const int lg   = l >> 4;

    if (tid < 192)       reinterpret_cast<f32x4*>(lds_b2)[tid]       = reinterpret_cast<const f32x4*>(b2g)[tid];
    else if (tid < 204)  reinterpret_cast<f32x4*>(lds_b1)[tid - 192] = reinterpret_cast<const f32x4*>(b1p)[tid - 192];
    else if (tid < 216)  reinterpret_cast<f32x4*>(lds_cs)[tid - 204] = reinterpret_cast<const f32x4*>(cs1)[tid - 204];
    __syncthreads();

    char* const wb = lds_buf[w];
    const size_t m0 = ((size_t)blockIdx.x * 4 + w) * 16;
    const char* const xg = (const char*)x + m0 * 3072;

    const bf16x8* __restrict__ w1f = reinterpret_cast<const bf16x8*>(w1p);
    const bf16x8* __restrict__ w2f = reinterpret_cast<const bf16x8*>(w2p);

    // ================= G1: stage third 0 (1 KB contiguous per instr) ==========
    {
        f32x4 xv[16];
        #pragma unroll
        for (int r = 0; r < 16; ++r)
            xv[r] = *reinterpret_cast<const f32x4*>(xg + r * 3072 + l * 16);
        #pragma unroll
        for (int r = 0; r < 16; ++r) {
            u16x4 pk;
            #pragma unroll
            for (int e = 0; e < 4; ++e) pk[e] = f2bf(xv[r][e]);
            *reinterpret_cast<u16x4*>(wb + r * 528 + l * 8) = pk;   // [16][264] bf16
        }
    }

    f32x4 acc1[3];
    #pragma unroll
    for (int nt = 0; nt < 3; ++nt) { acc1[nt][0]=0.f; acc1[nt][1]=0.f; acc1[nt][2]=0.f; acc1[nt][3]=0.f; }
    float rs = 0.f, rq = 0.f;

    #pragma unroll 1
    for (int j = 0; j < 3; ++j) {
        // (a) w1 fragments for this third — OLDEST in FIFO (waits on these
        //     never force retirement of the younger x stream)
        bf16x8 w1v[24];
        #pragma unroll
        for (int q = 0; q < 24; ++q) w1v[q] = w1f[(j * 24 + q) * 64 + l];
        // (b) contiguous stage-loads for third j+1 (HBM stream)
        f32x4 xn[16];
        if (j < 2) {
            #pragma unroll
            for (int r = 0; r < 16; ++r)
                xn[r] = *reinterpret_cast<const f32x4*>(xg + r * 3072 + (j + 1) * 1024 + l * 16);
        }
        SB0();   // pin loads above compute (compiler re-sinks otherwise)
        // (c) compute third j from buf[j&1]: 8 ktiles, frags via ds_read_b128
        const char* bb = wb + (j & 1) * 8448;
        #pragma unroll
        for (int ktl = 0; ktl < 8; ++ktl) {
            const bf16x8 xf = *reinterpret_cast<const bf16x8*>(bb + lrow * 528 + ktl * 64 + lg * 16);
            #pragma unroll
            for (int e = 0; e < 8; ++e) { const float xe = b2f(xf[e]); rs += xe; rq += xe * xe; }
            acc1[0] = __builtin_amdgcn_mfma_f32_16x16x32_bf16(w1v[ktl*3+0], xf, acc1[0], 0, 0, 0);
            acc1[1] = __builtin_amdgcn_mfma_f32_16x16x32_bf16(w1v[ktl*3+1], xf, acc1[1], 0, 0, 0);
            acc1[2] = __builtin_amdgcn_mfma_f32_16x16x32_bf16(w1v[ktl*3+2], xf, acc1[2], 0, 0, 0);
        }
        // (d) convert + write third j+1 (HBM latency hidden under (c))
        if (j < 2) {
            #pragma unroll
            for (int r = 0; r < 16; ++r) {
                u16x4 pk;
                #pragma unroll
                for (int e = 0; e < 4; ++e) pk[e] = f2bf(xn[r][e]);
                *reinterpret_cast<u16x4*>(wb + ((j + 1) & 1) * 8448 + r * 528 + l * 8) = pk;
            }
        }
    }

    // ---- stats reduce + LN fixup + QuickGELU -> hid (aliases wb) ----
    rs += __shfl_xor(rs, 16); rs += __shfl_xor(rs, 32);
    rq += __shfl_xor(rq, 16); rq += __shfl_xor(rq, 32);
    const float mu   = rs * (1.f / 768.f);
    const float var  = rq * (1.f / 768.f) - mu * mu;
    const float rstd = rsqrtf(var + 1e-5f);

    unsigned short* const hid = reinterpret_cast<unsigned short*>(wb);  // [16][72]
    *reinterpret_cast<unsigned long long*>(hid + (l >> 2) * 72 + 48 + (l & 3) * 4) = 0ull;
    #pragma unroll
    for (int nt = 0; nt < 3; ++nt) {
        const int c4 = nt * 16 + 4 * lg;
        const f32x4 bb = *reinterpret_cast<const f32x4*>(&lds_b1[c4]);
        const f32x4 cs = *reinterpret_cast<const f32x4*>(&lds_cs[c4]);
        u16x4 pk;
        #pragma unroll
        for (int r = 0; r < 4; ++r) {
            const float h = rstd * (acc1[nt][r] - mu * cs[r]) + bb[r];
            const float g = h / (1.f + __expf(-1.702f * h));
            pk[r] = f2bf(g);
        }
        *reinterpret_cast<u16x4*>(hid + lrow * 72 + c4) = pk;
    }
    // wave-synchronous handoff into regs (hid area is reused right after)
    const bf16x8 a2_0 = *reinterpret_cast<const bf16x8*>(hid + lrow * 72 + 8 * lg);
    const bf16x8 a2_1 = *reinterpret_cast<const bf16x8*>(hid + lrow * 72 + 8 * lg + 32);

    // ================= G2: 3 thirds x 16 ctiles; contiguous 1 KB stores =======
    const float* __restrict__ xres = x + (m0 + lrow) * CDIM;
    #pragma unroll 1
    for (int t3 = 0; t3 < 3; ++t3) {
        f32x4 res[16];
        #pragma unroll
        for (int i = 0; i < 16; ++i)
            res[i] = *reinterpret_cast<const f32x4*>(xres + (t3 * 16 + i) * 16 + 4 * lg);
        #pragma unroll
        for (int i = 0; i < 16; ++i) {
            const int ct = t3 * 16 + i;
            f32x4 a = {0.f, 0.f, 0.f, 0.f};
            a = __builtin_amdgcn_mfma_f32_16x16x32_bf16(w2f[ct * 64 + l],        a2_0, a, 0, 0, 0);
            a = __builtin_amdgcn_mfma_f32_16x16x32_bf16(w2f[(48 + ct) * 64 + l], a2_1, a, 0, 0, 0);
            const f32x4 bb = *reinterpret_cast<const f32x4*>(&lds_b2[ct * 16 + 4 * lg]);
            f32x4 o;
            #pragma unroll
            for (int r = 0; r < 4; ++r) o[r] = a[r] + bb[r] + res[i][r];
            // epilogue -> LDS out-third [16][260] f32 (fragment-order write)
            *reinterpret_cast<f32x4*>(wb + lrow * 1040 + (i * 16 + 4 * lg) * 4) = o;
        }
        // contiguous stores: 16 instrs x 1 KB (lane i <- bytes i*16 of row)
        #pragma unroll
        for (int r = 0; r < 16; ++r) {
            const f32x4 v = *reinterpret_cast<const f32x4*>(wb + r * 1040 + l * 16);
            *reinterpret_cast<f32x4*>((char*)out + (m0 + r) * 3072 + t3 * 1024 + l * 16) = v;
        }
    }
}

extern "C" void kernel_launch(void* const* d_in, const int* in_sizes, int n_in,
                              void* d_out, int out_size, void* d_ws, size_t ws_size,
                              hipStream_t stream)
{
    const float* x     = (const float*)d_in[0];
    const float* W1    = (const float*)d_in[1];
    const float* b1    = (const float*)d_in[2];
    const float* W2    = (const float*)d_in[3];
    const float* b2    = (const float*)d_in[4];
    const float* gamma = (const float*)d_in[5];
    const float* beta  = (const float*)d_in[6];
    float* out = (float*)d_out;

    unsigned short* w1p = (unsigned short*)d_ws;     // 72 frags * 1 KB = 73728 B
    unsigned short* w2p = w1p + 24 * 3 * 64 * 8;     // 96 frags * 1 KB = 98304 B
    float* b1p = (float*)(w2p + 2 * 48 * 64 * 8);    // 48 f32
    float* cs1 = b1p + 64;                           // 48 f32 (16B-aligned gap)

    const int M = in_sizes[0] / CDIM;   // 131072 rows
    const int blocks = M / 64;          // 2048 blocks x 4 waves x 16 rows

    prep_kernel<<<dim3(43), dim3(256), 0, stream>>>(W1, b1, W2, gamma, beta, w1p, w2p, b1p, cs1);
    mlp_kernel<<<dim3(blocks), dim3(256), 0, stream>>>(x, b2, w1p, w2p, b1p, cs1, out);
}